// Round 14
// baseline (454.487 us; speedup 1.0000x reference)
//
#include <hip/hip_runtime.h>
#include <hip/hip_bf16.h>

#define N_NODES 50000
#define E_EDGES 800000
#define HD 512
#define H_HEADS 4
#define D_DIM 128
#define N_PAD 53248  // 13 * 4096, zero-padded degree array for vectorized scan

typedef __attribute__((ext_vector_type(8))) short bf16x8;
typedef __attribute__((ext_vector_type(4))) float f32x4;
typedef __attribute__((ext_vector_type(2))) float f32x2;

__device__ __forceinline__ unsigned short f2b(float f) {
  unsigned u = __float_as_uint(f);
  u += 0x7FFFu + ((u >> 16) & 1u);  // RNE
  return (unsigned short)(u >> 16);
}
__device__ __forceinline__ float b2f(unsigned short s) {
  return __uint_as_float(((unsigned)s) << 16);
}
__device__ __forceinline__ float lrelu(float v) { return v > 0.f ? v : 0.2f * v; }
__device__ __forceinline__ float sel4(float a, float b, float c, float d, int h) {
  return h == 0 ? a : (h == 1 ? b : (h == 2 ? c : d));
}
__device__ __forceinline__ float sel4v(float4 v, int h) {
  return sel4(v.x, v.y, v.z, v.w, h);
}

#define GLOAD_LDS16(g, l)                                             \
  __builtin_amdgcn_global_load_lds(                                   \
      (const __attribute__((address_space(1))) void*)(g),             \
      (__attribute__((address_space(3))) void*)(l), 16, 0, 0)

// ---------------- prep: input cast + all W transposes in one kernel ----------------
// idx < 800000: cast nfeats (4 f32 each). Next 262144: transpose W1/W2/W3.
__global__ void prep_kernel(const float* __restrict__ nfeats, unsigned short* __restrict__ xb,
                            const float* __restrict__ W1, const float* __restrict__ W2,
                            const float* __restrict__ W3,
                            unsigned short* __restrict__ WT1, unsigned short* __restrict__ WT2,
                            unsigned short* __restrict__ WT3) {
  int idx = blockIdx.x * blockDim.x + threadIdx.x;
  const int NCAST = N_NODES * 256 / 4;  // 3.2M elems, 4 per thread
  if (idx < NCAST) {
    float4 v = *(const float4*)(nfeats + (size_t)idx * 4);
    ushort4 o;
    o.x = f2b(v.x); o.y = f2b(v.y); o.z = f2b(v.z); o.w = f2b(v.w);
    *(ushort4*)(xb + (size_t)idx * 4) = o;
    return;
  }
  int base = idx - NCAST;
  const float* W;
  unsigned short* WT;
  int K;
  if (base < 131072) {
    W = W1; WT = WT1; K = 256;
  } else if (base < 196608) {
    W = W2; WT = WT2; K = 128; base -= 131072;
  } else if (base < 262144) {
    W = W3; WT = WT3; K = 128; base -= 196608;
  } else {
    return;
  }
  int k = base / HD, c = base & (HD - 1);
  WT[(size_t)c * K + k] = f2b(W[(size_t)k * HD + c]);
}

// ---------------- LDS-tiled MFMA GEMM -> fp8 featq + fused el/er (R11 config) ----------------
// BM=128, BN=256 (=2 heads), BK=64; 8 waves (2 row x 4 col), wave computes 64x64.
__global__ __launch_bounds__(512) void gemm_mfma(const unsigned short* __restrict__ X,
                                                 const unsigned short* __restrict__ WT,
                                                 unsigned char* __restrict__ featq,
                                                 const float* __restrict__ al,
                                                 const float* __restrict__ ar,
                                                 float* __restrict__ el, float* __restrict__ er,
                                                 int K) {
  __shared__ unsigned short Atile[128 * 64];   // 16KB
  __shared__ unsigned short Btile[256 * 64];   // 32KB
  __shared__ float eds[2][2][2][128];          // [el/er][half][head_local][row] 8KB
  const int tid = threadIdx.x;
  const int w = tid >> 6, l = tid & 63;
  const int wr = w >> 2, wc = w & 3;
  const int row0 = blockIdx.x * 128;
  const int by = blockIdx.y;       // head pair
  const int col0 = by * 256;
  const int fr = l & 15;
  const int g = l >> 4;
  const int fk = g * 8;
  f32x4 acc[4][4] = {};

  for (int k0 = 0; k0 < K; k0 += 64) {
#pragma unroll
    for (int j = 0; j < 2; ++j) {
      int idx = j * 512 + tid;
      int row = idx >> 3;
      int ksw = ((idx & 7) << 3) ^ ((row & 7) << 3);
      int arow = row0 + row;
      if (arow >= N_NODES) arow = N_NODES - 1;
      GLOAD_LDS16(X + (size_t)arow * K + k0 + ksw,
                  (char*)Atile + j * 8192 + w * 1024);
    }
#pragma unroll
    for (int j = 0; j < 4; ++j) {
      int idx = j * 512 + tid;
      int row = idx >> 3;  // 0..255
      int ksw = ((idx & 7) << 3) ^ ((row & 7) << 3);
      GLOAD_LDS16(WT + (size_t)(col0 + row) * K + k0 + ksw,
                  (char*)Btile + j * 8192 + w * 1024);
    }
    __syncthreads();
#pragma unroll
    for (int kk = 0; kk < 64; kk += 32) {
      const int kel2 = (kk + fk) * 2;
      bf16x8 af[4], bf[4];
#pragma unroll
      for (int m = 0; m < 4; ++m) {
        int arow = wr * 64 + m * 16 + fr;
        af[m] = *(const bf16x8*)((const char*)Atile + arow * 128 + (kel2 ^ ((arow & 7) << 4)));
        int bcol = wc * 64 + m * 16 + fr;
        bf[m] = *(const bf16x8*)((const char*)Btile + bcol * 128 + (kel2 ^ ((bcol & 7) << 4)));
      }
#pragma unroll
      for (int m = 0; m < 4; ++m)
#pragma unroll
        for (int n = 0; n < 4; ++n)
          acc[m][n] = __builtin_amdgcn_mfma_f32_16x16x32_bf16(af[m], bf[n], acc[m][n], 0, 0, 0);
    }
    __syncthreads();
  }

  // ---- epilogue 1: fp8 store; D mapping col=l&15, row=g*4+i ----
#pragma unroll
  for (int m = 0; m < 4; ++m) {
#pragma unroll
    for (int i = 0; i < 4; ++i) {
      int r = row0 + wr * 64 + m * 16 + g * 4 + i;
      if (r < N_NODES) {
#pragma unroll
        for (int n = 0; n < 4; ++n) {
          int b = __builtin_amdgcn_cvt_pk_fp8_f32(acc[m][n][i], acc[m][n][i], 0, false);
          featq[(size_t)r * HD + col0 + wc * 64 + n * 16 + fr] = (unsigned char)(b & 0xFF);
        }
      }
    }
  }

  // ---- epilogue 2: el/er partial dots; wave covers (head hl, half) cols ----
  const int hl = wc >> 1, half = wc & 1;
  const int h = by * 2 + hl;
  float alk[4], ark[4];
#pragma unroll
  for (int n = 0; n < 4; ++n) {
    int c = h * D_DIM + half * 64 + n * 16 + fr;
    alk[n] = al[c];
    ark[n] = ar[c];
  }
#pragma unroll
  for (int m = 0; m < 4; ++m) {
#pragma unroll
    for (int i = 0; i < 4; ++i) {
      float pel = 0.f, per = 0.f;
#pragma unroll
      for (int n = 0; n < 4; ++n) {
        pel = fmaf(acc[m][n][i], alk[n], pel);
        per = fmaf(acc[m][n][i], ark[n], per);
      }
#pragma unroll
      for (int o = 1; o < 16; o <<= 1) {
        pel += __shfl_xor(pel, o);
        per += __shfl_xor(per, o);
      }
      if (fr == 0) {
        int rloc = wr * 64 + m * 16 + g * 4 + i;
        eds[0][half][hl][rloc] = pel;
        eds[1][half][hl][rloc] = per;
      }
    }
  }
  __syncthreads();
  {
    int row = tid >> 2, q = tid & 3;
    int hl2 = q & 1, sel = q >> 1;
    int r = row0 + row;
    if (r < N_NODES) {
      float v = eds[sel][0][hl2][row] + eds[sel][1][hl2][row];
      float* dst = (sel ? er : el);
      dst[(size_t)r * 4 + by * 2 + hl2] = v;
    }
  }
}

// ---------------- CSR build ----------------
__global__ void histo_kernel(const int* __restrict__ dst, unsigned* __restrict__ deg) {
  int e = blockIdx.x * blockDim.x + threadIdx.x;
  if (e >= E_EDGES) return;
  atomicAdd(&deg[dst[e]], 1u);
}

__global__ void scan_local(const unsigned* __restrict__ deg, unsigned* __restrict__ off,
                           unsigned* __restrict__ bsum) {
  __shared__ unsigned warp_sums[16];
  const int tid = threadIdx.x;
  const int wid = tid >> 6;
  int i = blockIdx.x * 4096 + tid * 4;
  uint4 v = *(const uint4*)(deg + i);
  unsigned sm = v.x + v.y + v.z + v.w;
  unsigned x = sm;
#pragma unroll
  for (int o = 1; o < 64; o <<= 1) {
    unsigned y = __shfl_up(x, o);
    if ((tid & 63) >= o) x += y;
  }
  if ((tid & 63) == 63) warp_sums[wid] = x;
  __syncthreads();
  if (tid < 16) {
    unsigned s = warp_sums[tid];
#pragma unroll
    for (int o = 1; o < 16; o <<= 1) {
      unsigned y = __shfl_up(s, o);
      if (tid >= o) s += y;
    }
    warp_sums[tid] = s;
  }
  __syncthreads();
  unsigned wprev = (wid > 0) ? warp_sums[wid - 1] : 0u;
  unsigned ex = wprev + (x - sm);
  uint4 o4;
  o4.x = ex;
  o4.y = ex + v.x;
  o4.z = o4.y + v.y;
  o4.w = o4.z + v.z;
  *(uint4*)(off + i) = o4;
  if (tid == 1023) bsum[blockIdx.x] = warp_sums[15];
}

__global__ void scan_bsums(unsigned* __restrict__ bsum) {
  int t = threadIdx.x;  // 64
  unsigned v = (t < 13) ? bsum[t] : 0u;
  unsigned x = v;
#pragma unroll
  for (int o = 1; o < 16; o <<= 1) {
    unsigned y = __shfl_up(x, o);
    if (t >= o) x += y;
  }
  if (t < 13) bsum[t] = x - v;  // exclusive
}

__global__ void scan_add(unsigned* __restrict__ off, const unsigned* __restrict__ bsum,
                         unsigned* __restrict__ cursor) {
  int i = (blockIdx.x * 1024 + threadIdx.x) * 4;
  unsigned p = bsum[blockIdx.x];  // one scan_add block == one scan_local block (4096 elems)
  uint4 v = *(const uint4*)(off + i);
  v.x += p; v.y += p; v.z += p; v.w += p;
  *(uint4*)(off + i) = v;
  *(uint4*)(cursor + i) = v;
}

__global__ void scatter_kernel(const int* __restrict__ src, const int* __restrict__ dst,
                               unsigned* __restrict__ cursor, int* __restrict__ csr_src) {
  int e = blockIdx.x * blockDim.x + threadIdx.x;
  if (e >= E_EDGES) return;
  int d = dst[e];
  unsigned pos = atomicAdd(&cursor[d], 1u);
  csr_src[pos] = src[e];
}

// ---------------- fused edge-softmax + aggregate + bias/relu/head-mean ----------------
// 4 nodes per 256-thread block, wave wv owns node blockIdx.x*4+wv.
// Body per wave is EXACTLY the R11 single-wave version (4-burst gather).
__global__ __launch_bounds__(256) void agg_fused(const unsigned* __restrict__ off,
                                                 const int* __restrict__ csr_src,
                                                 const float* __restrict__ el,
                                                 const float* __restrict__ er,
                                                 const unsigned char* __restrict__ featq,
                                                 const float* __restrict__ bias,
                                                 unsigned short* __restrict__ hbuf) {
  __shared__ float4 ws4[4][64];
  const int wv = threadIdx.x >> 6, t = threadIdx.x & 63;
  const int n = blockIdx.x * 4 + wv;
  if (n >= N_NODES) return;
  const int h = t >> 4, d0 = (t & 15) * 8;
  const unsigned beg = off[n];
  const int deg = (int)(off[n + 1] - beg);
  const float NEG = -3.0e38f;
  float4 rr = *(const float4*)(er + (size_t)n * 4);
  f32x2 acc2[4] = {};

  if (deg <= 64) {
    float4 v = {NEG, NEG, NEG, NEG};
    if (t < deg) {
      int s = csr_src[beg + t];
      float4 ll = *(const float4*)(el + (size_t)s * 4);
      v.x = lrelu(ll.x + rr.x);
      v.y = lrelu(ll.y + rr.y);
      v.z = lrelu(ll.z + rr.z);
      v.w = lrelu(ll.w + rr.w);
    }
    float m0 = v.x, m1 = v.y, m2 = v.z, m3 = v.w;
#pragma unroll
    for (int o = 32; o >= 1; o >>= 1) {
      m0 = fmaxf(m0, __shfl_xor(m0, o));
      m1 = fmaxf(m1, __shfl_xor(m1, o));
      m2 = fmaxf(m2, __shfl_xor(m2, o));
      m3 = fmaxf(m3, __shfl_xor(m3, o));
    }
    float4 ev = {0.f, 0.f, 0.f, 0.f};
    if (t < deg) {
      ev.x = __expf(v.x - m0);
      ev.y = __expf(v.y - m1);
      ev.z = __expf(v.z - m2);
      ev.w = __expf(v.w - m3);
    }
    float s0 = ev.x, s1 = ev.y, s2 = ev.z, s3 = ev.w;
#pragma unroll
    for (int o = 32; o >= 1; o >>= 1) {
      s0 += __shfl_xor(s0, o);
      s1 += __shfl_xor(s1, o);
      s2 += __shfl_xor(s2, o);
      s3 += __shfl_xor(s3, o);
    }
    ws4[wv][t] = ev;  // intra-wave LDS: lgkmcnt-ordered, no barrier needed
    float invh = 1.0f / sel4(s0, s1, s2, s3, h);
    const unsigned char* fq = featq + t * 8;
    for (int j0 = 0; j0 < deg; j0 += 4) {
      int i1 = (j0 + 1 < deg) ? j0 + 1 : j0;
      int i2 = (j0 + 2 < deg) ? j0 + 2 : j0;
      int i3 = (j0 + 3 < deg) ? j0 + 3 : j0;
      int sa = csr_src[beg + j0], sb = csr_src[beg + i1];
      int sc = csr_src[beg + i2], sd = csr_src[beg + i3];
      uint2 qa = *(const uint2*)(fq + (size_t)sa * HD);
      uint2 qb = *(const uint2*)(fq + (size_t)sb * HD);
      uint2 qc = *(const uint2*)(fq + (size_t)sc * HD);
      uint2 qd = *(const uint2*)(fq + (size_t)sd * HD);
      float wa = sel4v(ws4[wv][j0], h) * invh;
      float wb = sel4v(ws4[wv][i1], h) * invh;
      float wc2 = sel4v(ws4[wv][i2], h) * invh;
      float wd = sel4v(ws4[wv][i3], h) * invh;
      if (j0 + 1 >= deg) wb = 0.f;
      if (j0 + 2 >= deg) wc2 = 0.f;
      if (j0 + 3 >= deg) wd = 0.f;
      f32x2 w2;
      w2 = (f32x2){wa, wa};
      acc2[0] += __builtin_amdgcn_cvt_pk_f32_fp8((int)qa.x, false) * w2;
      acc2[1] += __builtin_amdgcn_cvt_pk_f32_fp8((int)qa.x, true) * w2;
      acc2[2] += __builtin_amdgcn_cvt_pk_f32_fp8((int)qa.y, false) * w2;
      acc2[3] += __builtin_amdgcn_cvt_pk_f32_fp8((int)qa.y, true) * w2;
      w2 = (f32x2){wb, wb};
      acc2[0] += __builtin_amdgcn_cvt_pk_f32_fp8((int)qb.x, false) * w2;
      acc2[1] += __builtin_amdgcn_cvt_pk_f32_fp8((int)qb.x, true) * w2;
      acc2[2] += __builtin_amdgcn_cvt_pk_f32_fp8((int)qb.y, false) * w2;
      acc2[3] += __builtin_amdgcn_cvt_pk_f32_fp8((int)qb.y, true) * w2;
      w2 = (f32x2){wc2, wc2};
      acc2[0] += __builtin_amdgcn_cvt_pk_f32_fp8((int)qc.x, false) * w2;
      acc2[1] += __builtin_amdgcn_cvt_pk_f32_fp8((int)qc.x, true) * w2;
      acc2[2] += __builtin_amdgcn_cvt_pk_f32_fp8((int)qc.y, false) * w2;
      acc2[3] += __builtin_amdgcn_cvt_pk_f32_fp8((int)qc.y, true) * w2;
      w2 = (f32x2){wd, wd};
      acc2[0] += __builtin_amdgcn_cvt_pk_f32_fp8((int)qd.x, false) * w2;
      acc2[1] += __builtin_amdgcn_cvt_pk_f32_fp8((int)qd.x, true) * w2;
      acc2[2] += __builtin_amdgcn_cvt_pk_f32_fp8((int)qd.y, false) * w2;
      acc2[3] += __builtin_amdgcn_cvt_pk_f32_fp8((int)qd.y, true) * w2;
    }
  } else {
    float m[4] = {NEG, NEG, NEG, NEG};
    for (int j = t; j < deg; j += 64) {
      int s = csr_src[beg + j];
      float4 ll = *(const float4*)(el + (size_t)s * 4);
      m[0] = fmaxf(m[0], lrelu(ll.x + rr.x));
      m[1] = fmaxf(m[1], lrelu(ll.y + rr.y));
      m[2] = fmaxf(m[2], lrelu(ll.z + rr.z));
      m[3] = fmaxf(m[3], lrelu(ll.w + rr.w));
    }
#pragma unroll
    for (int o = 32; o >= 1; o >>= 1) {
      m[0] = fmaxf(m[0], __shfl_xor(m[0], o));
      m[1] = fmaxf(m[1], __shfl_xor(m[1], o));
      m[2] = fmaxf(m[2], __shfl_xor(m[2], o));
      m[3] = fmaxf(m[3], __shfl_xor(m[3], o));
    }
    float sm[4] = {0.f, 0.f, 0.f, 0.f};
    for (int j = t; j < deg; j += 64) {
      int s = csr_src[beg + j];
      float4 ll = *(const float4*)(el + (size_t)s * 4);
      sm[0] += __expf(lrelu(ll.x + rr.x) - m[0]);
      sm[1] += __expf(lrelu(ll.y + rr.y) - m[1]);
      sm[2] += __expf(lrelu(ll.z + rr.z) - m[2]);
      sm[3] += __expf(lrelu(ll.w + rr.w) - m[3]);
    }
#pragma unroll
    for (int o = 32; o >= 1; o >>= 1) {
      sm[0] += __shfl_xor(sm[0], o);
      sm[1] += __shfl_xor(sm[1], o);
      sm[2] += __shfl_xor(sm[2], o);
      sm[3] += __shfl_xor(sm[3], o);
    }
    float mh = sel4(m[0], m[1], m[2], m[3], h);
    float ih = 1.0f / sel4(sm[0], sm[1], sm[2], sm[3], h);
    float rrh = sel4(rr.x, rr.y, rr.z, rr.w, h);
    for (int j = 0; j < deg; ++j) {
      int sj = csr_src[beg + j];
      float llh = el[(size_t)sj * 4 + h];
      float w = __expf(lrelu(llh + rrh) - mh) * ih;
      uint2 q = *(const uint2*)(featq + (size_t)sj * HD + t * 8);
      f32x2 w2 = {w, w};
      acc2[0] += __builtin_amdgcn_cvt_pk_f32_fp8((int)q.x, false) * w2;
      acc2[1] += __builtin_amdgcn_cvt_pk_f32_fp8((int)q.x, true) * w2;
      acc2[2] += __builtin_amdgcn_cvt_pk_f32_fp8((int)q.y, false) * w2;
      acc2[3] += __builtin_amdgcn_cvt_pk_f32_fp8((int)q.y, true) * w2;
    }
  }

  const float* bp = bias + h * D_DIM + d0;
  float4 b0 = *(const float4*)bp, b1 = *(const float4*)(bp + 4);
  float bv[8] = {b0.x, b0.y, b0.z, b0.w, b1.x, b1.y, b1.z, b1.w};
  float r[8];
#pragma unroll
  for (int i = 0; i < 8; ++i) r[i] = fmaxf(acc2[i >> 1][i & 1] + bv[i], 0.f);
#pragma unroll
  for (int i = 0; i < 8; ++i) {
    r[i] += __shfl_xor(r[i], 16);
    r[i] += __shfl_xor(r[i], 32);
  }
  if (h == 0) {
    uint4 o;
    o.x = (unsigned)f2b(r[0] * 0.25f) | ((unsigned)f2b(r[1] * 0.25f) << 16);
    o.y = (unsigned)f2b(r[2] * 0.25f) | ((unsigned)f2b(r[3] * 0.25f) << 16);
    o.z = (unsigned)f2b(r[4] * 0.25f) | ((unsigned)f2b(r[5] * 0.25f) << 16);
    o.w = (unsigned)f2b(r[6] * 0.25f) | ((unsigned)f2b(r[7] * 0.25f) << 16);
    *(uint4*)(hbuf + (size_t)n * D_DIM + d0) = o;
  }
}

// ---------------- readout ----------------
__global__ void colsum(const unsigned short* __restrict__ hbuf, float* __restrict__ hg) {
  int d = threadIdx.x;  // 128
  float s = 0.0f;
  for (int n = blockIdx.x; n < N_NODES; n += gridDim.x)
    s += b2f(hbuf[(size_t)n * D_DIM + d]);
  atomicAdd(&hg[d], s);
}

__global__ void final_k(const float* __restrict__ hg, const float* __restrict__ Wc,
                        const float* __restrict__ bc, float* __restrict__ out) {
  int l = threadIdx.x;  // 64
  float v = hg[l] * Wc[l] + hg[l + 64] * Wc[l + 64];
#pragma unroll
  for (int off = 32; off >= 1; off >>= 1) v += __shfl_xor(v, off);
  if (l == 0) {
    float x = v * (1.0f / N_NODES) + bc[0];
    out[0] = 1.0f / (1.0f + expf(-x));
  }
}

extern "C" void kernel_launch(void* const* d_in, const int* in_sizes, int n_in,
                              void* d_out, int out_size, void* d_ws, size_t ws_size,
                              hipStream_t stream) {
  const float* nfeats = (const float*)d_in[0];
  const float* W1 = (const float*)d_in[1];
  const float* al1 = (const float*)d_in[2];
  const float* ar1 = (const float*)d_in[3];
  const float* b1 = (const float*)d_in[4];
  const float* W2 = (const float*)d_in[5];
  const float* al2 = (const float*)d_in[6];
  const float* ar2 = (const float*)d_in[7];
  const float* b2 = (const float*)d_in[8];
  const float* W3 = (const float*)d_in[9];
  const float* al3 = (const float*)d_in[10];
  const float* ar3 = (const float*)d_in[11];
  const float* b3 = (const float*)d_in[12];
  const float* Wc = (const float*)d_in[13];
  const float* bc = (const float*)d_in[14];
  const int* src = (const int*)d_in[15];
  const int* dst = (const int*)d_in[16];
  float* out = (float*)d_out;

  // ---- workspace carve (256B aligned regions) ----
  char* p = (char*)d_ws;
  auto carve = [&](size_t bytes) {
    char* r = p;
    p += (bytes + 255) & ~(size_t)255;
    return r;
  };
  float* el = (float*)carve((size_t)N_NODES * 4 * 4);
  float* er = (float*)carve((size_t)N_NODES * 4 * 4);
  float* hg = (float*)carve(512);
  unsigned* deg = (unsigned*)carve((size_t)N_PAD * 4);
  unsigned* offv = (unsigned*)carve((size_t)(N_PAD + 4) * 4);
  unsigned* cursor = (unsigned*)carve((size_t)N_PAD * 4);
  unsigned* bsum = (unsigned*)carve(64 * 4);
  int* csr_src = (int*)carve((size_t)E_EDGES * 4);
  unsigned char* featq = (unsigned char*)carve((size_t)N_NODES * HD);
  unsigned short* hbufb = (unsigned short*)carve((size_t)N_NODES * D_DIM * 2);
  unsigned short* xb = (unsigned short*)carve((size_t)(N_NODES + 128) * 256 * 2);
  unsigned short* WT1 = (unsigned short*)carve((size_t)HD * 256 * 2);
  unsigned short* WT2 = (unsigned short*)carve((size_t)HD * 128 * 2);
  unsigned short* WT3 = (unsigned short*)carve((size_t)HD * 128 * 2);

  // ---- build CSR once (dst constant across layers) ----
  hipMemsetAsync(deg, 0, (size_t)N_PAD * sizeof(unsigned), stream);
  histo_kernel<<<(E_EDGES + 255) / 256, 256, 0, stream>>>(dst, deg);
  scan_local<<<13, 1024, 0, stream>>>(deg, offv, bsum);
  scan_bsums<<<1, 64, 0, stream>>>(bsum);
  scan_add<<<13, 1024, 0, stream>>>(offv, bsum, cursor);
  scatter_kernel<<<(E_EDGES + 255) / 256, 256, 0, stream>>>(src, dst, cursor, csr_src);

  // input cast + all weight prep in one kernel
  prep_kernel<<<(N_NODES * 64 + 262144 + 255) / 256, 256, 0, stream>>>(
      nfeats, xb, W1, W2, W3, WT1, WT2, WT3);

  auto run_layer = [&](const unsigned short* X, int K, const unsigned short* WT,
                       const float* alv, const float* arv, const float* bv) {
    dim3 g((N_NODES + 127) / 128, 2);
    gemm_mfma<<<g, 512, 0, stream>>>(X, WT, featq, alv, arv, el, er, K);
    agg_fused<<<(N_NODES + 3) / 4, 256, 0, stream>>>(offv, csr_src, el, er, featq, bv, hbufb);
  };

  run_layer(xb, 256, WT1, al1, ar1, b1);
  run_layer(hbufb, 128, WT2, al2, ar2, b2);
  run_layer(hbufb, 128, WT3, al3, ar3, b3);

  hipMemsetAsync(hg, 0, 512, stream);
  colsum<<<1024, 128, 0, stream>>>(hbufb, hg);
  final_k<<<1, 64, 0, stream>>>(hg, Wc, bc, out);
}

// Round 15
// 437.892 us; speedup vs baseline: 1.0379x; 1.0379x over previous
//
#include <hip/hip_runtime.h>
#include <hip/hip_bf16.h>

#define N_NODES 50000
#define E_EDGES 800000
#define HD 512
#define H_HEADS 4
#define D_DIM 128
#define N_PAD 53248  // 13 * 4096, zero-padded degree array for vectorized scan

typedef __attribute__((ext_vector_type(8))) short bf16x8;
typedef __attribute__((ext_vector_type(4))) float f32x4;
typedef __attribute__((ext_vector_type(2))) float f32x2;

__device__ __forceinline__ unsigned short f2b(float f) {
  unsigned u = __float_as_uint(f);
  u += 0x7FFFu + ((u >> 16) & 1u);  // RNE
  return (unsigned short)(u >> 16);
}
__device__ __forceinline__ float b2f(unsigned short s) {
  return __uint_as_float(((unsigned)s) << 16);
}
__device__ __forceinline__ float lrelu(float v) { return v > 0.f ? v : 0.2f * v; }
__device__ __forceinline__ float sel4(float a, float b, float c, float d, int h) {
  return h == 0 ? a : (h == 1 ? b : (h == 2 ? c : d));
}
__device__ __forceinline__ float sel4v(float4 v, int h) {
  return sel4(v.x, v.y, v.z, v.w, h);
}

#define GLOAD_LDS16(g, l)                                             \
  __builtin_amdgcn_global_load_lds(                                   \
      (const __attribute__((address_space(1))) void*)(g),             \
      (__attribute__((address_space(3))) void*)(l), 16, 0, 0)

// ---------------- prep: input cast + all W transposes in one kernel ----------------
__global__ void prep_kernel(const float* __restrict__ nfeats, unsigned short* __restrict__ xb,
                            const float* __restrict__ W1, const float* __restrict__ W2,
                            const float* __restrict__ W3,
                            unsigned short* __restrict__ WT1, unsigned short* __restrict__ WT2,
                            unsigned short* __restrict__ WT3) {
  int idx = blockIdx.x * blockDim.x + threadIdx.x;
  const int NCAST = N_NODES * 256 / 4;  // 3.2M elems, 4 per thread
  if (idx < NCAST) {
    float4 v = *(const float4*)(nfeats + (size_t)idx * 4);
    ushort4 o;
    o.x = f2b(v.x); o.y = f2b(v.y); o.z = f2b(v.z); o.w = f2b(v.w);
    *(ushort4*)(xb + (size_t)idx * 4) = o;
    return;
  }
  int base = idx - NCAST;
  const float* W;
  unsigned short* WT;
  int K;
  if (base < 131072) {
    W = W1; WT = WT1; K = 256;
  } else if (base < 196608) {
    W = W2; WT = WT2; K = 128; base -= 131072;
  } else if (base < 262144) {
    W = W3; WT = WT3; K = 128; base -= 196608;
  } else {
    return;
  }
  int k = base / HD, c = base & (HD - 1);
  WT[(size_t)c * K + k] = f2b(W[(size_t)k * HD + c]);
}

// ---------------- LDS-tiled MFMA GEMM -> fp8 featq + fused el/er (R11 config) ----------------
// BM=128, BN=256 (=2 heads), BK=64; 8 waves (2 row x 4 col), wave computes 64x64.
__global__ __launch_bounds__(512) void gemm_mfma(const unsigned short* __restrict__ X,
                                                 const unsigned short* __restrict__ WT,
                                                 unsigned char* __restrict__ featq,
                                                 const float* __restrict__ al,
                                                 const float* __restrict__ ar,
                                                 float* __restrict__ el, float* __restrict__ er,
                                                 int K) {
  __shared__ unsigned short Atile[128 * 64];   // 16KB
  __shared__ unsigned short Btile[256 * 64];   // 32KB
  __shared__ float eds[2][2][2][128];          // [el/er][half][head_local][row] 8KB
  const int tid = threadIdx.x;
  const int w = tid >> 6, l = tid & 63;
  const int wr = w >> 2, wc = w & 3;
  const int row0 = blockIdx.x * 128;
  const int by = blockIdx.y;       // head pair
  const int col0 = by * 256;
  const int fr = l & 15;
  const int g = l >> 4;
  const int fk = g * 8;
  f32x4 acc[4][4] = {};

  for (int k0 = 0; k0 < K; k0 += 64) {
#pragma unroll
    for (int j = 0; j < 2; ++j) {
      int idx = j * 512 + tid;
      int row = idx >> 3;
      int ksw = ((idx & 7) << 3) ^ ((row & 7) << 3);
      int arow = row0 + row;
      if (arow >= N_NODES) arow = N_NODES - 1;
      GLOAD_LDS16(X + (size_t)arow * K + k0 + ksw,
                  (char*)Atile + j * 8192 + w * 1024);
    }
#pragma unroll
    for (int j = 0; j < 4; ++j) {
      int idx = j * 512 + tid;
      int row = idx >> 3;  // 0..255
      int ksw = ((idx & 7) << 3) ^ ((row & 7) << 3);
      GLOAD_LDS16(WT + (size_t)(col0 + row) * K + k0 + ksw,
                  (char*)Btile + j * 8192 + w * 1024);
    }
    __syncthreads();
#pragma unroll
    for (int kk = 0; kk < 64; kk += 32) {
      const int kel2 = (kk + fk) * 2;
      bf16x8 af[4], bf[4];
#pragma unroll
      for (int m = 0; m < 4; ++m) {
        int arow = wr * 64 + m * 16 + fr;
        af[m] = *(const bf16x8*)((const char*)Atile + arow * 128 + (kel2 ^ ((arow & 7) << 4)));
        int bcol = wc * 64 + m * 16 + fr;
        bf[m] = *(const bf16x8*)((const char*)Btile + bcol * 128 + (kel2 ^ ((bcol & 7) << 4)));
      }
#pragma unroll
      for (int m = 0; m < 4; ++m)
#pragma unroll
        for (int n = 0; n < 4; ++n)
          acc[m][n] = __builtin_amdgcn_mfma_f32_16x16x32_bf16(af[m], bf[n], acc[m][n], 0, 0, 0);
    }
    __syncthreads();
  }

  // ---- epilogue 1: fp8 store; D mapping col=l&15, row=g*4+i ----
#pragma unroll
  for (int m = 0; m < 4; ++m) {
#pragma unroll
    for (int i = 0; i < 4; ++i) {
      int r = row0 + wr * 64 + m * 16 + g * 4 + i;
      if (r < N_NODES) {
#pragma unroll
        for (int n = 0; n < 4; ++n) {
          int b = __builtin_amdgcn_cvt_pk_fp8_f32(acc[m][n][i], acc[m][n][i], 0, false);
          featq[(size_t)r * HD + col0 + wc * 64 + n * 16 + fr] = (unsigned char)(b & 0xFF);
        }
      }
    }
  }

  // ---- epilogue 2: el/er partial dots; wave covers (head hl, half) cols ----
  const int hl = wc >> 1, half = wc & 1;
  const int h = by * 2 + hl;
  float alk[4], ark[4];
#pragma unroll
  for (int n = 0; n < 4; ++n) {
    int c = h * D_DIM + half * 64 + n * 16 + fr;
    alk[n] = al[c];
    ark[n] = ar[c];
  }
#pragma unroll
  for (int m = 0; m < 4; ++m) {
#pragma unroll
    for (int i = 0; i < 4; ++i) {
      float pel = 0.f, per = 0.f;
#pragma unroll
      for (int n = 0; n < 4; ++n) {
        pel = fmaf(acc[m][n][i], alk[n], pel);
        per = fmaf(acc[m][n][i], ark[n], per);
      }
#pragma unroll
      for (int o = 1; o < 16; o <<= 1) {
        pel += __shfl_xor(pel, o);
        per += __shfl_xor(per, o);
      }
      if (fr == 0) {
        int rloc = wr * 64 + m * 16 + g * 4 + i;
        eds[0][half][hl][rloc] = pel;
        eds[1][half][hl][rloc] = per;
      }
    }
  }
  __syncthreads();
  {
    int row = tid >> 2, q = tid & 3;
    int hl2 = q & 1, sel = q >> 1;
    int r = row0 + row;
    if (r < N_NODES) {
      float v = eds[sel][0][hl2][row] + eds[sel][1][hl2][row];
      float* dst = (sel ? er : el);
      dst[(size_t)r * 4 + by * 2 + hl2] = v;
    }
  }
}

// ---------------- CSR build ----------------
__global__ void histo_kernel(const int* __restrict__ dst, unsigned* __restrict__ deg) {
  int e = blockIdx.x * blockDim.x + threadIdx.x;
  if (e >= E_EDGES) return;
  atomicAdd(&deg[dst[e]], 1u);
}

__global__ void scan_local(const unsigned* __restrict__ deg, unsigned* __restrict__ off,
                           unsigned* __restrict__ bsum) {
  __shared__ unsigned warp_sums[16];
  const int tid = threadIdx.x;
  const int wid = tid >> 6;
  int i = blockIdx.x * 4096 + tid * 4;
  uint4 v = *(const uint4*)(deg + i);
  unsigned sm = v.x + v.y + v.z + v.w;
  unsigned x = sm;
#pragma unroll
  for (int o = 1; o < 64; o <<= 1) {
    unsigned y = __shfl_up(x, o);
    if ((tid & 63) >= o) x += y;
  }
  if ((tid & 63) == 63) warp_sums[wid] = x;
  __syncthreads();
  if (tid < 16) {
    unsigned s = warp_sums[tid];
#pragma unroll
    for (int o = 1; o < 16; o <<= 1) {
      unsigned y = __shfl_up(s, o);
      if (tid >= o) s += y;
    }
    warp_sums[tid] = s;
  }
  __syncthreads();
  unsigned wprev = (wid > 0) ? warp_sums[wid - 1] : 0u;
  unsigned ex = wprev + (x - sm);
  uint4 o4;
  o4.x = ex;
  o4.y = ex + v.x;
  o4.z = o4.y + v.y;
  o4.w = o4.z + v.z;
  *(uint4*)(off + i) = o4;
  if (tid == 1023) bsum[blockIdx.x] = warp_sums[15];
}

__global__ void scan_bsums(unsigned* __restrict__ bsum) {
  int t = threadIdx.x;  // 64
  unsigned v = (t < 13) ? bsum[t] : 0u;
  unsigned x = v;
#pragma unroll
  for (int o = 1; o < 16; o <<= 1) {
    unsigned y = __shfl_up(x, o);
    if (t >= o) x += y;
  }
  if (t < 13) bsum[t] = x - v;  // exclusive
}

__global__ void scan_add(unsigned* __restrict__ off, const unsigned* __restrict__ bsum,
                         unsigned* __restrict__ cursor) {
  int i = (blockIdx.x * 1024 + threadIdx.x) * 4;
  unsigned p = bsum[blockIdx.x];  // one scan_add block == one scan_local block (4096 elems)
  uint4 v = *(const uint4*)(off + i);
  v.x += p; v.y += p; v.z += p; v.w += p;
  *(uint4*)(off + i) = v;
  *(uint4*)(cursor + i) = v;
}

__global__ void scatter_kernel(const int* __restrict__ src, const int* __restrict__ dst,
                               unsigned* __restrict__ cursor, int* __restrict__ csr_src) {
  int e = blockIdx.x * blockDim.x + threadIdx.x;
  if (e >= E_EDGES) return;
  int d = dst[e];
  unsigned pos = atomicAdd(&cursor[d], 1u);
  csr_src[pos] = src[e];
}

// ---------------- fused edge-softmax + aggregate + bias/relu/head-mean ----------------
// R11 config (measured floor): 1 wave per node; thread t: head h=t>>4, dims d0=(t&15)*8..+7
__global__ __launch_bounds__(64) void agg_fused(const unsigned* __restrict__ off,
                                                const int* __restrict__ csr_src,
                                                const float* __restrict__ el,
                                                const float* __restrict__ er,
                                                const unsigned char* __restrict__ featq,
                                                const float* __restrict__ bias,
                                                unsigned short* __restrict__ hbuf) {
  __shared__ float4 ws4[64];
  const int n = blockIdx.x, t = threadIdx.x;
  const int h = t >> 4, d0 = (t & 15) * 8;
  const unsigned beg = off[n];
  const int deg = (int)(off[n + 1] - beg);
  const float NEG = -3.0e38f;
  float4 rr = *(const float4*)(er + (size_t)n * 4);
  f32x2 acc2[4] = {};

  if (deg <= 64) {
    float4 v = {NEG, NEG, NEG, NEG};
    if (t < deg) {
      int s = csr_src[beg + t];
      float4 ll = *(const float4*)(el + (size_t)s * 4);
      v.x = lrelu(ll.x + rr.x);
      v.y = lrelu(ll.y + rr.y);
      v.z = lrelu(ll.z + rr.z);
      v.w = lrelu(ll.w + rr.w);
    }
    float m0 = v.x, m1 = v.y, m2 = v.z, m3 = v.w;
#pragma unroll
    for (int o = 32; o >= 1; o >>= 1) {
      m0 = fmaxf(m0, __shfl_xor(m0, o));
      m1 = fmaxf(m1, __shfl_xor(m1, o));
      m2 = fmaxf(m2, __shfl_xor(m2, o));
      m3 = fmaxf(m3, __shfl_xor(m3, o));
    }
    float4 ev = {0.f, 0.f, 0.f, 0.f};
    if (t < deg) {
      ev.x = __expf(v.x - m0);
      ev.y = __expf(v.y - m1);
      ev.z = __expf(v.z - m2);
      ev.w = __expf(v.w - m3);
    }
    float s0 = ev.x, s1 = ev.y, s2 = ev.z, s3 = ev.w;
#pragma unroll
    for (int o = 32; o >= 1; o >>= 1) {
      s0 += __shfl_xor(s0, o);
      s1 += __shfl_xor(s1, o);
      s2 += __shfl_xor(s2, o);
      s3 += __shfl_xor(s3, o);
    }
    ws4[t] = ev;  // zeros beyond deg -> padded lanes contribute 0
    float invh = 1.0f / sel4(s0, s1, s2, s3, h);
    __syncthreads();
    const unsigned char* fq = featq + t * 8;
    for (int j0 = 0; j0 < deg; j0 += 4) {
      int i1 = (j0 + 1 < deg) ? j0 + 1 : j0;
      int i2 = (j0 + 2 < deg) ? j0 + 2 : j0;
      int i3 = (j0 + 3 < deg) ? j0 + 3 : j0;
      int sa = csr_src[beg + j0], sb = csr_src[beg + i1];
      int sc = csr_src[beg + i2], sd = csr_src[beg + i3];
      uint2 qa = *(const uint2*)(fq + (size_t)sa * HD);
      uint2 qb = *(const uint2*)(fq + (size_t)sb * HD);
      uint2 qc = *(const uint2*)(fq + (size_t)sc * HD);
      uint2 qd = *(const uint2*)(fq + (size_t)sd * HD);
      float wa = sel4v(ws4[j0], h) * invh;
      float wb = sel4v(ws4[i1], h) * invh;
      float wc2 = sel4v(ws4[i2], h) * invh;
      float wd = sel4v(ws4[i3], h) * invh;
      if (j0 + 1 >= deg) wb = 0.f;
      if (j0 + 2 >= deg) wc2 = 0.f;
      if (j0 + 3 >= deg) wd = 0.f;
      f32x2 w2;
      w2 = (f32x2){wa, wa};
      acc2[0] += __builtin_amdgcn_cvt_pk_f32_fp8((int)qa.x, false) * w2;
      acc2[1] += __builtin_amdgcn_cvt_pk_f32_fp8((int)qa.x, true) * w2;
      acc2[2] += __builtin_amdgcn_cvt_pk_f32_fp8((int)qa.y, false) * w2;
      acc2[3] += __builtin_amdgcn_cvt_pk_f32_fp8((int)qa.y, true) * w2;
      w2 = (f32x2){wb, wb};
      acc2[0] += __builtin_amdgcn_cvt_pk_f32_fp8((int)qb.x, false) * w2;
      acc2[1] += __builtin_amdgcn_cvt_pk_f32_fp8((int)qb.x, true) * w2;
      acc2[2] += __builtin_amdgcn_cvt_pk_f32_fp8((int)qb.y, false) * w2;
      acc2[3] += __builtin_amdgcn_cvt_pk_f32_fp8((int)qb.y, true) * w2;
      w2 = (f32x2){wc2, wc2};
      acc2[0] += __builtin_amdgcn_cvt_pk_f32_fp8((int)qc.x, false) * w2;
      acc2[1] += __builtin_amdgcn_cvt_pk_f32_fp8((int)qc.x, true) * w2;
      acc2[2] += __builtin_amdgcn_cvt_pk_f32_fp8((int)qc.y, false) * w2;
      acc2[3] += __builtin_amdgcn_cvt_pk_f32_fp8((int)qc.y, true) * w2;
      w2 = (f32x2){wd, wd};
      acc2[0] += __builtin_amdgcn_cvt_pk_f32_fp8((int)qd.x, false) * w2;
      acc2[1] += __builtin_amdgcn_cvt_pk_f32_fp8((int)qd.x, true) * w2;
      acc2[2] += __builtin_amdgcn_cvt_pk_f32_fp8((int)qd.y, false) * w2;
      acc2[3] += __builtin_amdgcn_cvt_pk_f32_fp8((int)qd.y, true) * w2;
    }
  } else {
    float m[4] = {NEG, NEG, NEG, NEG};
    for (int j = t; j < deg; j += 64) {
      int s = csr_src[beg + j];
      float4 ll = *(const float4*)(el + (size_t)s * 4);
      m[0] = fmaxf(m[0], lrelu(ll.x + rr.x));
      m[1] = fmaxf(m[1], lrelu(ll.y + rr.y));
      m[2] = fmaxf(m[2], lrelu(ll.z + rr.z));
      m[3] = fmaxf(m[3], lrelu(ll.w + rr.w));
    }
#pragma unroll
    for (int o = 32; o >= 1; o >>= 1) {
      m[0] = fmaxf(m[0], __shfl_xor(m[0], o));
      m[1] = fmaxf(m[1], __shfl_xor(m[1], o));
      m[2] = fmaxf(m[2], __shfl_xor(m[2], o));
      m[3] = fmaxf(m[3], __shfl_xor(m[3], o));
    }
    float sm[4] = {0.f, 0.f, 0.f, 0.f};
    for (int j = t; j < deg; j += 64) {
      int s = csr_src[beg + j];
      float4 ll = *(const float4*)(el + (size_t)s * 4);
      sm[0] += __expf(lrelu(ll.x + rr.x) - m[0]);
      sm[1] += __expf(lrelu(ll.y + rr.y) - m[1]);
      sm[2] += __expf(lrelu(ll.z + rr.z) - m[2]);
      sm[3] += __expf(lrelu(ll.w + rr.w) - m[3]);
    }
#pragma unroll
    for (int o = 32; o >= 1; o >>= 1) {
      sm[0] += __shfl_xor(sm[0], o);
      sm[1] += __shfl_xor(sm[1], o);
      sm[2] += __shfl_xor(sm[2], o);
      sm[3] += __shfl_xor(sm[3], o);
    }
    float mh = sel4(m[0], m[1], m[2], m[3], h);
    float ih = 1.0f / sel4(sm[0], sm[1], sm[2], sm[3], h);
    float rrh = sel4(rr.x, rr.y, rr.z, rr.w, h);
    for (int j = 0; j < deg; ++j) {
      int sj = csr_src[beg + j];
      float llh = el[(size_t)sj * 4 + h];
      float w = __expf(lrelu(llh + rrh) - mh) * ih;
      uint2 q = *(const uint2*)(featq + (size_t)sj * HD + t * 8);
      f32x2 w2 = {w, w};
      acc2[0] += __builtin_amdgcn_cvt_pk_f32_fp8((int)q.x, false) * w2;
      acc2[1] += __builtin_amdgcn_cvt_pk_f32_fp8((int)q.x, true) * w2;
      acc2[2] += __builtin_amdgcn_cvt_pk_f32_fp8((int)q.y, false) * w2;
      acc2[3] += __builtin_amdgcn_cvt_pk_f32_fp8((int)q.y, true) * w2;
    }
  }

  const float* bp = bias + h * D_DIM + d0;
  float4 b0 = *(const float4*)bp, b1 = *(const float4*)(bp + 4);
  float bv[8] = {b0.x, b0.y, b0.z, b0.w, b1.x, b1.y, b1.z, b1.w};
  float r[8];
#pragma unroll
  for (int i = 0; i < 8; ++i) r[i] = fmaxf(acc2[i >> 1][i & 1] + bv[i], 0.f);
#pragma unroll
  for (int i = 0; i < 8; ++i) {
    r[i] += __shfl_xor(r[i], 16);
    r[i] += __shfl_xor(r[i], 32);
  }
  if (h == 0) {
    uint4 o;
    o.x = (unsigned)f2b(r[0] * 0.25f) | ((unsigned)f2b(r[1] * 0.25f) << 16);
    o.y = (unsigned)f2b(r[2] * 0.25f) | ((unsigned)f2b(r[3] * 0.25f) << 16);
    o.z = (unsigned)f2b(r[4] * 0.25f) | ((unsigned)f2b(r[5] * 0.25f) << 16);
    o.w = (unsigned)f2b(r[6] * 0.25f) | ((unsigned)f2b(r[7] * 0.25f) << 16);
    *(uint4*)(hbuf + (size_t)n * D_DIM + d0) = o;
  }
}

// ---------------- readout ----------------
__global__ void colsum(const unsigned short* __restrict__ hbuf, float* __restrict__ hg) {
  int d = threadIdx.x;  // 128
  float s = 0.0f;
  for (int n = blockIdx.x; n < N_NODES; n += gridDim.x)
    s += b2f(hbuf[(size_t)n * D_DIM + d]);
  atomicAdd(&hg[d], s);
}

__global__ void final_k(const float* __restrict__ hg, const float* __restrict__ Wc,
                        const float* __restrict__ bc, float* __restrict__ out) {
  int l = threadIdx.x;  // 64
  float v = hg[l] * Wc[l] + hg[l + 64] * Wc[l + 64];
#pragma unroll
  for (int off = 32; off >= 1; off >>= 1) v += __shfl_xor(v, off);
  if (l == 0) {
    float x = v * (1.0f / N_NODES) + bc[0];
    out[0] = 1.0f / (1.0f + expf(-x));
  }
}

extern "C" void kernel_launch(void* const* d_in, const int* in_sizes, int n_in,
                              void* d_out, int out_size, void* d_ws, size_t ws_size,
                              hipStream_t stream) {
  const float* nfeats = (const float*)d_in[0];
  const float* W1 = (const float*)d_in[1];
  const float* al1 = (const float*)d_in[2];
  const float* ar1 = (const float*)d_in[3];
  const float* b1 = (const float*)d_in[4];
  const float* W2 = (const float*)d_in[5];
  const float* al2 = (const float*)d_in[6];
  const float* ar2 = (const float*)d_in[7];
  const float* b2 = (const float*)d_in[8];
  const float* W3 = (const float*)d_in[9];
  const float* al3 = (const float*)d_in[10];
  const float* ar3 = (const float*)d_in[11];
  const float* b3 = (const float*)d_in[12];
  const float* Wc = (const float*)d_in[13];
  const float* bc = (const float*)d_in[14];
  const int* src = (const int*)d_in[15];
  const int* dst = (const int*)d_in[16];
  float* out = (float*)d_out;

  // ---- workspace carve (256B aligned regions) ----
  char* p = (char*)d_ws;
  auto carve = [&](size_t bytes) {
    char* r = p;
    p += (bytes + 255) & ~(size_t)255;
    return r;
  };
  float* el = (float*)carve((size_t)N_NODES * 4 * 4);
  float* er = (float*)carve((size_t)N_NODES * 4 * 4);
  float* hg = (float*)carve(512);
  unsigned* deg = (unsigned*)carve((size_t)N_PAD * 4);
  unsigned* offv = (unsigned*)carve((size_t)(N_PAD + 4) * 4);
  unsigned* cursor = (unsigned*)carve((size_t)N_PAD * 4);
  unsigned* bsum = (unsigned*)carve(64 * 4);
  int* csr_src = (int*)carve((size_t)E_EDGES * 4);
  unsigned char* featq = (unsigned char*)carve((size_t)N_NODES * HD);
  unsigned short* hbufb = (unsigned short*)carve((size_t)N_NODES * D_DIM * 2);
  unsigned short* xb = (unsigned short*)carve((size_t)(N_NODES + 128) * 256 * 2);
  unsigned short* WT1 = (unsigned short*)carve((size_t)HD * 256 * 2);
  unsigned short* WT2 = (unsigned short*)carve((size_t)HD * 128 * 2);
  unsigned short* WT3 = (unsigned short*)carve((size_t)HD * 128 * 2);

  // ---- build CSR once (dst constant across layers) ----
  hipMemsetAsync(deg, 0, (size_t)N_PAD * sizeof(unsigned), stream);
  histo_kernel<<<(E_EDGES + 255) / 256, 256, 0, stream>>>(dst, deg);
  scan_local<<<13, 1024, 0, stream>>>(deg, offv, bsum);
  scan_bsums<<<1, 64, 0, stream>>>(bsum);
  scan_add<<<13, 1024, 0, stream>>>(offv, bsum, cursor);
  scatter_kernel<<<(E_EDGES + 255) / 256, 256, 0, stream>>>(src, dst, cursor, csr_src);

  // input cast + all weight prep in one kernel
  prep_kernel<<<(N_NODES * 64 + 262144 + 255) / 256, 256, 0, stream>>>(
      nfeats, xb, W1, W2, W3, WT1, WT2, WT3);

  auto run_layer = [&](const unsigned short* X, int K, const unsigned short* WT,
                       const float* alv, const float* arv, const float* bv) {
    dim3 g((N_NODES + 127) / 128, 2);
    gemm_mfma<<<g, 512, 0, stream>>>(X, WT, featq, alv, arv, el, er, K);
    agg_fused<<<N_NODES, 64, 0, stream>>>(offv, csr_src, el, er, featq, bv, hbufb);
  };

  run_layer(xb, 256, WT1, al1, ar1, b1);
  run_layer(hbufb, 128, WT2, al2, ar2, b2);
  run_layer(hbufb, 128, WT3, al3, ar3, b3);

  hipMemsetAsync(hg, 0, 512, stream);
  colsum<<<1024, 128, 0, stream>>>(hbufb, hg);
  final_k<<<1, 64, 0, stream>>>(hg, Wc, bc, out);
}